// Round 15
// baseline (272.249 us; speedup 1.0000x reference)
//
#include <hip/hip_runtime.h>
#include <hip/hip_bf16.h>

typedef __attribute__((ext_vector_type(8))) short bf16x8_t;
typedef __attribute__((ext_vector_type(4))) float f32x4_t;
typedef __attribute__((ext_vector_type(4))) unsigned int u32x4_t;

#define XP_BYTES 55115776u   // 4*16*58*58*128*2
#define WT_BYTES 2359296u    // 144 units * 256 oc * 32 k * 2B (frag-native)

typedef __attribute__((address_space(1))) const unsigned int ga_u32_t;
typedef __attribute__((address_space(3))) unsigned int lds_u32_t;

__device__ __forceinline__ void g2l16(const void* g, void* l) {
  __builtin_amdgcn_global_load_lds((ga_u32_t*)g, (lds_u32_t*)l, 16, 0, 0);
}

// ---------------------------------------------------------------------------
// prep_x: x (16,256,56,56) f32 -> xp (4,16,58,58,128) bf16, inner = hl*64+c.
// Writes its own zero borders (rows 0/57, cols 0/57) -> no xp memset needed.
// ---------------------------------------------------------------------------
__global__ __launch_bounds__(256) void prep_x(const float* __restrict__ x,
                                              __hip_bfloat16* __restrict__ xp) {
  __shared__ float ls[64 * 57];
  int blk = blockIdx.x;            // (g, b, h) : 4*16*56 = 3584
  int g = blk / 896;
  int r = blk - g * 896;
  int b = r / 56;
  int h = r - b * 56;
  int tid = threadIdx.x;
  const float* src = x + (size_t)(b * 256 + g * 64) * 3136 + h * 56;
  for (int i = tid; i < 64 * 56; i += 256) {
    int c = i / 56, w = i - c * 56;
    ls[c * 57 + w] = src[(size_t)c * 3136 + w];
  }
  __syncthreads();
  __hip_bfloat16* gbbase = xp + (size_t)(g * 16 + b) * 58 * 58 * 128;
  __hip_bfloat16* dst = gbbase + ((size_t)(h + 1) * 58 + 1) * 128;
  int wp = tid >> 7;
  int inner = tid & 127;
  int hl = inner >> 6, c = inner & 63;
  for (int w0 = 0; w0 < 56; w0 += 2) {
    int w = w0 + wp;
    float v = ls[c * 57 + w];
    __hip_bfloat16 hi = __float2bfloat16(v);
    __hip_bfloat16 val = hl ? __float2bfloat16(v - __bfloat162float(hi)) : hi;
    dst[(size_t)w * 128 + inner] = val;
  }
  __hip_bfloat16 z = __float2bfloat16(0.0f);
  {
    __hip_bfloat16* rowp = gbbase + (size_t)(h + 1) * 58 * 128;
    if (tid < 128) rowp[inner] = z;              // col 0
    else           rowp[57 * 128 + inner] = z;   // col 57
  }
  if (h == 0) {
    for (int i = tid; i < 58 * 128; i += 256) gbbase[i] = z;    // row 0
  }
  if (h == 55) {
    __hip_bfloat16* r57 = gbbase + (size_t)57 * 58 * 128;
    for (int i = tid; i < 58 * 128; i += 256) r57[i] = z;       // row 57
  }
}

// ---------------------------------------------------------------------------
// prep_w: weight (256,256,3,3) f32 -> FRAG-NATIVE layout (16x16x32 MFMA):
//   wtf[u][wq 0..3][ni 0..3][lane 0..63][8 bf16]
// u = g*36 + sgn*18 + tap*2 + cc; lane's 16B = its MFMA B-operand fragment:
// oc = wq*64 + ni*16 + (l&15), k = (l>>4)*8 + e, channel c = cc*32 + k.
// ---------------------------------------------------------------------------
__global__ __launch_bounds__(256) void prep_w(const float* __restrict__ wgt,
                                              const float* __restrict__ wsc,
                                              unsigned short* __restrict__ wtf) {
  int idx = blockIdx.x * 256 + threadIdx.x;   // 147456 = 144*4*4*64
  if (idx >= 147456) return;
  int l = idx & 63;
  int ni = (idx >> 6) & 3;
  int wq = (idx >> 8) & 3;
  int u = idx >> 10;                          // 0..143
  int g = u / 36;
  int r36 = u - g * 36;
  int sgn = (r36 >= 18) ? 1 : 0;
  int r18 = r36 - sgn * 18;
  int tap = r18 >> 1, cc = r18 & 1;
  int oc = wq * 64 + ni * 16 + (l & 15);
  float inv = 1.f / wsc[g];
  unsigned short pk[8];
#pragma unroll
  for (int e = 0; e < 8; ++e) {
    int c = cc * 32 + ((l >> 4) << 3) + e;
    float w = wgt[(size_t)oc * 2304 + (g * 64 + c) * 9 + tap] * inv;
    if (sgn) w = -w;
    float q = rintf(fminf(fmaxf(w, 0.f), 3.f));
    union { __hip_bfloat16 h; unsigned short s; } cv;
    cv.h = __float2bfloat16(q);
    pk[e] = cv.s;
  }
  u32x4_t v;
  v[0] = (unsigned)pk[0] | ((unsigned)pk[1] << 16);
  v[1] = (unsigned)pk[2] | ((unsigned)pk[3] << 16);
  v[2] = (unsigned)pk[4] | ((unsigned)pk[5] << 16);
  v[3] = (unsigned)pk[6] | ((unsigned)pk[7] << 16);
  *(u32x4_t*)(wtf + (size_t)idx * 8) = v;
}

// ---------------------------------------------------------------------------
// Main conv — R7 skeleton + ONE-SWEEP A-FRAG PREFETCH (register-neutral
// software pipeline). The 32-MFMA block per half-unit is split into two
// 16-MFMA sweeps; the NEXT half-unit's 4 hi-frag ds_reads issue after the
// hi-sweep (WAR on ahi resolves at MFMA issue), the 4 lo-frag reads after
// the lo-sweep. Prefetch distance per read group: >= 1 sweep (~78 cyc)
// instead of 0 — hides most of the ~120-150 cyc LDS latency head that
// capped R7/R13/R14 at 43% MfmaUtil.
// Grid 784 = 16 b x 49 aligned 64-px tiles. BM=64 px, BN=256 oc. 256 thr =
// 4 waves (N quarters), wave tile 64x64, 2 blocks/CU (LDS 64KB).
// ---------------------------------------------------------------------------
#define MEMPIN asm volatile("" ::: "memory")
#define BAR __builtin_amdgcn_s_barrier()
#define VMCNT0 asm volatile("s_waitcnt vmcnt(0)" ::: "memory")
#define LGKM0 asm volatile("s_waitcnt lgkmcnt(0)" ::: "memory")

__global__ __launch_bounds__(256, 2) void conv_mfma(
    const unsigned short* __restrict__ xp, const unsigned short* __restrict__ wtf,
    const float* __restrict__ wsc, const float* __restrict__ psp,
    const float* __restrict__ psn, float* __restrict__ out) {
  __shared__ char Astrip[65536];               // 4 rows x 64 px x 256B

  const int bid = blockIdx.x;
  const int wg = (bid & 7) * 98 + (bid >> 3);  // bijective XCD swizzle (784=8*98)
  const int b = wg / 49;
  const int t = wg - b * 49;
  const int r0 = (t << 6) / 56;                // top padded xp-row of strip

  const int tid = threadIdx.x;
  const int wv = tid >> 6;                     // N quarter 0..3
  const int l = tid & 63;

  // ---- A frag pixel bases (strip-relative, 64-px row stride)
  int pxb[4];
#pragma unroll
  for (int mi = 0; mi < 4; ++mi) {
    int m = (t << 6) + mi * 16 + (l & 15);
    int rv = m / 56, w = m - rv * 56;
    pxb[mi] = ((rv - r0) << 6) + w;
  }

  // ---- scalars preloaded
  float w0s = wsc[0], w1s = wsc[1], w2s = wsc[2], w3s = wsc[3];
  float p0 = psp[0], p1 = psp[1], p2 = psp[2], p3 = psp[3];
  float n0 = psn[0], n1 = psn[1], n2 = psn[2], n3 = psn[3];

  f32x4_t acc[4][4], oacc[4][4];
  const f32x4_t fz = {0.f, 0.f, 0.f, 0.f};
#pragma unroll
  for (int i = 0; i < 4; ++i)
#pragma unroll
    for (int j = 0; j < 4; ++j) { acc[i][j] = fz; oacc[i][j] = fz; }

  const char* xg = (const char*)xp;
  const char* wtb = (const char*)wtf + (wv << 12) + (l << 4);  // per-lane B base
  const unsigned a_gbbase = (unsigned)((b * 3364 + r0 * 58) * 256);

  // stage the 64KB strip for group gg (16 loads/thread)
#define STAGE_STRIP(gg)                                                        \
  {                                                                            \
    const char* s_ = xg + (unsigned)(gg)*13778944u + a_gbbase;                 \
    _Pragma("unroll")                                                          \
    for (int k_ = 0; k_ < 16; ++k_) {                                          \
      int idx_ = tid + (k_ << 8);                                              \
      int px_ = idx_ >> 4, sl_ = idx_ & 15;                                    \
      int sr_ = px_ >> 6, xc_ = px_ & 63;                                      \
      g2l16(s_ + (sr_ * 58 + xc_) * 256 +                                      \
                (((sl_ & 8) | ((sl_ & 7) ^ (xc_ & 7))) << 4),                  \
            Astrip + idx_ * 16);                                               \
    }                                                                          \
  }

#define LOADB(d0, d1, d2, d3, uu)                                              \
  {                                                                            \
    const char* p_ = wtb + (unsigned)(uu) * 16384u;                            \
    d0 = *(const bf16x8_t*)(p_);                                               \
    d1 = *(const bf16x8_t*)(p_ + 1024);                                        \
    d2 = *(const bf16x8_t*)(p_ + 2048);                                        \
    d3 = *(const bf16x8_t*)(p_ + 3072);                                        \
  }

  // 4 hi-frag ds_reads for k-half cc_ at tap offset tyo_
#define READA_HI(cc_, tyo_)                                                    \
  {                                                                            \
    const int kj_ = ((cc_) << 2) + (l >> 4);                                   \
    _Pragma("unroll")                                                          \
    for (int mi = 0; mi < 4; ++mi) {                                           \
      int px_ = pxb[mi] + (tyo_);                                              \
      ahi[mi] = *(const bf16x8_t*)(Astrip + (px_ << 8) +                       \
                                   ((kj_ ^ (px_ & 7)) << 4));                  \
    }                                                                          \
  }

  // 4 lo-frag ds_reads (lo plane = +128B within the pixel's 256B line)
#define READA_LO(cc_, tyo_)                                                    \
  {                                                                            \
    const int kj_ = ((cc_) << 2) + (l >> 4);                                   \
    _Pragma("unroll")                                                          \
    for (int mi = 0; mi < 4; ++mi) {                                           \
      int px_ = pxb[mi] + (tyo_);                                              \
      alo[mi] = *(const bf16x8_t*)(Astrip + (px_ << 8) +                       \
                                   ((kj_ ^ (px_ & 7)) << 4) + 128);            \
    }                                                                          \
  }

  // one 16-MFMA sweep: frags AF x B0..3 (16 independent acc streams)
#define SWEEP16(AF, B0, B1, B2, B3)                                            \
  __builtin_amdgcn_s_setprio(1);                                               \
  _Pragma("unroll")                                                            \
  for (int mi = 0; mi < 4; ++mi) {                                             \
    acc[mi][0] = __builtin_amdgcn_mfma_f32_16x16x32_bf16(AF[mi], B0, acc[mi][0], 0, 0, 0); \
    acc[mi][1] = __builtin_amdgcn_mfma_f32_16x16x32_bf16(AF[mi], B1, acc[mi][1], 0, 0, 0); \
    acc[mi][2] = __builtin_amdgcn_mfma_f32_16x16x32_bf16(AF[mi], B2, acc[mi][2], 0, 0, 0); \
    acc[mi][3] = __builtin_amdgcn_mfma_f32_16x16x32_bf16(AF[mi], B3, acc[mi][3], 0, 0, 0); \
  }                                                                            \
  __builtin_amdgcn_s_setprio(0);

#define QUANTIZE(gg, ss)                                                       \
  {                                                                            \
    float sw = ((gg) & 2) ? (((gg) & 1) ? w3s : w2s) : (((gg) & 1) ? w1s : w0s); \
    float sp = ((gg) & 2) ? (((gg) & 1) ? p3 : p2) : (((gg) & 1) ? p1 : p0);   \
    float sn = ((gg) & 2) ? (((gg) & 1) ? n3 : n2) : (((gg) & 1) ? n1 : n0);   \
    float sq = (ss) ? sn : sp;                                                 \
    float rs = sw / sq;                                                        \
    float sm = (ss) ? -sq : sq;                                                \
    _Pragma("unroll")                                                          \
    for (int mi = 0; mi < 4; ++mi)                                             \
      _Pragma("unroll")                                                        \
      for (int ni = 0; ni < 4; ++ni)                                           \
        _Pragma("unroll")                                                      \
        for (int j = 0; j < 4; ++j) {                                          \
          float v = acc[mi][ni][j] * rs;                                       \
          v = fminf(fmaxf(v, -128.f), 127.f);                                  \
          oacc[mi][ni][j] += sm * rintf(v);                                    \
          acc[mi][ni][j] = 0.f;                                                \
        }                                                                      \
  }

  bf16x8_t ahi[4], alo[4];
  bf16x8_t bA0, bA1, bA2, bA3, bB0, bB1, bB2, bB3;

  // ---- prologue: strip(0) + B(0), B(1) in flight; then drain + prefetch u0
  STAGE_STRIP(0);
  MEMPIN;
  LOADB(bA0, bA1, bA2, bA3, 0);
  LOADB(bB0, bB1, bB2, bB3, 1);
  VMCNT0;
  BAR;
  MEMPIN;
  READA_HI(0, 0);                 // unit 0 frags (tap 0, cc 0)
  READA_LO(0, 0);

  int tap = 0, sgn = 0, g = 0;
  for (int v = 0; v < 72; ++v) {
    const int ty = tap / 3;
    const int tyo = (ty << 6) + (tap - ty * 3);
    const int tapN = (tap < 8) ? (tap + 1) : 0;
    const int tyN = tapN / 3;
    const int tyoN = (tyN << 6) + (tapN - tyN * 3);

    // ---- half-unit 2v (cc=0): frags already in ahi/alo (prefetched)
    SWEEP16(ahi, bA0, bA1, bA2, bA3);
    READA_HI(1, tyo);             // prefetch 2v+1 hi (WAR: ahi consumed)
    SWEEP16(alo, bA0, bA1, bA2, bA3);
    READA_LO(1, tyo);             // prefetch 2v+1 lo
    if (v < 71) { LOADB(bA0, bA1, bA2, bA3, 2 * v + 2); }

    // ---- half-unit 2v+1 (cc=1)
    SWEEP16(ahi, bB0, bB1, bB2, bB3);
    if (tap < 8) { READA_HI(0, tyoN); }    // prefetch next tap, cc=0, hi
    SWEEP16(alo, bB0, bB1, bB2, bB3);
    if (tap < 8) { READA_LO(0, tyoN); }    // prefetch next tap, cc=0, lo

    if (tap == 8) {
      QUANTIZE(g, sgn);
      if (v < 71) {
        if (sgn == 0) {
          // sign boundary: same strip — prefetch tap0/cc0 of sign 1
          READA_HI(0, 0);
          READA_LO(0, 0);
        } else {
          // group boundary: republish strip, then prefetch tap0/cc0
          LGKM0;
          BAR;
          MEMPIN;
          STAGE_STRIP(g + 1);
          VMCNT0;
          BAR;
          MEMPIN;
          READA_HI(0, 0);
          READA_LO(0, 0);
        }
      }
    }
    if (v < 71) { LOADB(bB0, bB1, bB2, bB3, 2 * v + 3); }

    if (++tap == 9) { tap = 0; g += sgn; sgn ^= 1; }
  }

  // ---- store (64-px tiles are image-row-aligned: no masking needed)
#pragma unroll
  for (int ni = 0; ni < 4; ++ni) {
    int oc = (wv << 6) + ni * 16 + (l & 15);
    float* orow = out + ((size_t)(b * 256 + oc)) * 3136;
#pragma unroll
    for (int mi = 0; mi < 4; ++mi) {
      int m0 = (t << 6) + mi * 16 + ((l >> 4) << 2);
#pragma unroll
      for (int j = 0; j < 4; ++j) {
        orow[m0 + j] = oacc[mi][ni][j];
      }
    }
  }
#undef STAGE_STRIP
#undef LOADB
#undef READA_HI
#undef READA_LO
#undef SWEEP16
#undef QUANTIZE
}

// ---------------------------------------------------------------------------
// Fallback (ws too small): direct conv with inline weight quantization.
// ---------------------------------------------------------------------------
__global__ __launch_bounds__(256) void naive_conv(
    const float* __restrict__ x, const float* __restrict__ wgt,
    const float* __restrict__ wsc, const float* __restrict__ psp,
    const float* __restrict__ psn, float* __restrict__ out) {
  int idx = blockIdx.x * 256 + threadIdx.x;
  if (idx >= 12845056) return;
  int b = idx / 802816;
  int r = idx - b * 802816;
  int oc = r / 3136;
  int hw = r - oc * 3136;
  int h = hw / 56, w = hw - (hw / 56) * 56;
  float o = 0.f;
  for (int g = 0; g < 4; ++g) {
    float sw = wsc[g];
    float inv = 1.f / sw;
    float pp = 0.f, pn = 0.f;
    for (int tap = 0; tap < 9; ++tap) {
      int y = h + tap / 3 - 1, xx = w + tap % 3 - 1;
      if (y < 0 || y > 55 || xx < 0 || xx > 55) continue;
      const float* xr = x + (size_t)(b * 256 + g * 64) * 3136 + y * 56 + xx;
      const float* wrr = wgt + (size_t)oc * 2304 + (size_t)(g * 64) * 9 + tap;
      for (int c = 0; c < 64; ++c) {
        float xv = xr[(size_t)c * 3136];
        float rv = wrr[c * 9] * inv;
        pp += xv * rintf(fminf(fmaxf(rv, 0.f), 3.f));
        pn += xv * rintf(fminf(fmaxf(-rv, 0.f), 3.f));
      }
    }
    float sp = psp[g], sn = psn[g];
    o += rintf(fminf(fmaxf(pp * (sw / sp), -128.f), 127.f)) * sp;
    o -= rintf(fminf(fmaxf(pn * (sw / sn), -128.f), 127.f)) * sn;
  }
  out[idx] = o;
}

extern "C" void kernel_launch(void* const* d_in, const int* in_sizes, int n_in,
                              void* d_out, int out_size, void* d_ws, size_t ws_size,
                              hipStream_t stream) {
  const float* x = (const float*)d_in[0];
  const float* wgt = (const float*)d_in[1];
  const float* wsc = (const float*)d_in[2];
  const float* psp = (const float*)d_in[3];
  const float* psn = (const float*)d_in[4];
  float* out = (float*)d_out;

  if (ws_size >= (size_t)XP_BYTES + (size_t)WT_BYTES) {
    unsigned short* xpw = (unsigned short*)d_ws;
    unsigned short* wtw = (unsigned short*)((char*)d_ws + XP_BYTES);
    prep_x<<<3584, 256, 0, stream>>>(x, (__hip_bfloat16*)xpw);
    prep_w<<<576, 256, 0, stream>>>(wgt, wsc, wtw);
    conv_mfma<<<784, 256, 0, stream>>>(xpw, wtw, wsc, psp, psn, out);
  } else {
    naive_conv<<<(12845056 + 255) / 256, 256, 0, stream>>>(x, wgt, wsc, psp, psn, out);
  }
}

// Round 16
// 239.311 us; speedup vs baseline: 1.1376x; 1.1376x over previous
//
#include <hip/hip_runtime.h>
#include <hip/hip_bf16.h>

typedef __attribute__((ext_vector_type(8))) short bf16x8_t;
typedef __attribute__((ext_vector_type(4))) float f32x4_t;
typedef __attribute__((ext_vector_type(4))) unsigned int u32x4_t;

#define XP_BYTES 55115776u   // 4*16*58*58*128*2
#define WT_BYTES 2359296u    // 144 units * 256 oc * 32 k * 2B (frag-native)

typedef __attribute__((address_space(1))) const unsigned int ga_u32_t;
typedef __attribute__((address_space(3))) unsigned int lds_u32_t;

__device__ __forceinline__ void g2l16(const void* g, void* l) {
  __builtin_amdgcn_global_load_lds((ga_u32_t*)g, (lds_u32_t*)l, 16, 0, 0);
}

// ---------------------------------------------------------------------------
// prep_x: x (16,256,56,56) f32 -> xp (4,16,58,58,128) bf16, inner = hl*64+c.
// Writes its own zero borders (rows 0/57, cols 0/57) -> no xp memset needed.
// ---------------------------------------------------------------------------
__global__ __launch_bounds__(256) void prep_x(const float* __restrict__ x,
                                              __hip_bfloat16* __restrict__ xp) {
  __shared__ float ls[64 * 57];
  int blk = blockIdx.x;            // (g, b, h) : 4*16*56 = 3584
  int g = blk / 896;
  int r = blk - g * 896;
  int b = r / 56;
  int h = r - b * 56;
  int tid = threadIdx.x;
  const float* src = x + (size_t)(b * 256 + g * 64) * 3136 + h * 56;
  for (int i = tid; i < 64 * 56; i += 256) {
    int c = i / 56, w = i - c * 56;
    ls[c * 57 + w] = src[(size_t)c * 3136 + w];
  }
  __syncthreads();
  __hip_bfloat16* gbbase = xp + (size_t)(g * 16 + b) * 58 * 58 * 128;
  __hip_bfloat16* dst = gbbase + ((size_t)(h + 1) * 58 + 1) * 128;
  int wp = tid >> 7;
  int inner = tid & 127;
  int hl = inner >> 6, c = inner & 63;
  for (int w0 = 0; w0 < 56; w0 += 2) {
    int w = w0 + wp;
    float v = ls[c * 57 + w];
    __hip_bfloat16 hi = __float2bfloat16(v);
    __hip_bfloat16 val = hl ? __float2bfloat16(v - __bfloat162float(hi)) : hi;
    dst[(size_t)w * 128 + inner] = val;
  }
  __hip_bfloat16 z = __float2bfloat16(0.0f);
  {
    __hip_bfloat16* rowp = gbbase + (size_t)(h + 1) * 58 * 128;
    if (tid < 128) rowp[inner] = z;              // col 0
    else           rowp[57 * 128 + inner] = z;   // col 57
  }
  if (h == 0) {
    for (int i = tid; i < 58 * 128; i += 256) gbbase[i] = z;    // row 0
  }
  if (h == 55) {
    __hip_bfloat16* r57 = gbbase + (size_t)57 * 58 * 128;
    for (int i = tid; i < 58 * 128; i += 256) r57[i] = z;       // row 57
  }
}

// ---------------------------------------------------------------------------
// prep_w: weight (256,256,3,3) f32 -> FRAG-NATIVE layout (16x16x32 MFMA):
//   wtf[u][wq 0..3][ni 0..3][lane 0..63][8 bf16]
// u = g*36 + sgn*18 + tap*2 + cc; lane's 16B = its MFMA B-operand fragment:
// oc = wq*64 + ni*16 + (l&15), k = (l>>4)*8 + e, channel c = cc*32 + k.
// ---------------------------------------------------------------------------
__global__ __launch_bounds__(256) void prep_w(const float* __restrict__ wgt,
                                              const float* __restrict__ wsc,
                                              unsigned short* __restrict__ wtf) {
  int idx = blockIdx.x * 256 + threadIdx.x;   // 147456 = 144*4*4*64
  if (idx >= 147456) return;
  int l = idx & 63;
  int ni = (idx >> 6) & 3;
  int wq = (idx >> 8) & 3;
  int u = idx >> 10;                          // 0..143
  int g = u / 36;
  int r36 = u - g * 36;
  int sgn = (r36 >= 18) ? 1 : 0;
  int r18 = r36 - sgn * 18;
  int tap = r18 >> 1, cc = r18 & 1;
  int oc = wq * 64 + ni * 16 + (l & 15);
  float inv = 1.f / wsc[g];
  unsigned short pk[8];
#pragma unroll
  for (int e = 0; e < 8; ++e) {
    int c = cc * 32 + ((l >> 4) << 3) + e;
    float w = wgt[(size_t)oc * 2304 + (g * 64 + c) * 9 + tap] * inv;
    if (sgn) w = -w;
    float q = rintf(fminf(fmaxf(w, 0.f), 3.f));
    union { __hip_bfloat16 h; unsigned short s; } cv;
    cv.h = __float2bfloat16(q);
    pk[e] = cv.s;
  }
  u32x4_t v;
  v[0] = (unsigned)pk[0] | ((unsigned)pk[1] << 16);
  v[1] = (unsigned)pk[2] | ((unsigned)pk[3] << 16);
  v[2] = (unsigned)pk[4] | ((unsigned)pk[5] << 16);
  v[3] = (unsigned)pk[6] | ((unsigned)pk[7] << 16);
  *(u32x4_t*)(wtf + (size_t)idx * 8) = v;
}

// ---------------------------------------------------------------------------
// Main conv — best-measured configuration (240us, R13): R7 skeleton +
// two-sweep MFMA order. Grid 784 = 16 b x 49 aligned 64-px tiles.
// BM=64 px, BN=256 oc. 256 thr = 4 waves (N quarters), wave tile 64x64,
// 2 blocks/CU (LDS 64KB). Register state = 128 VGPR + 128 AGPR = 256/wave
// (the 2-waves/SIMD occupancy boundary — hard cap for this tile).
// A: 4-row strip (64KB LDS), staged once per group; taps = LDS offsets;
//    conflict-free XOR swizzle. Barriers only at group boundaries.
// B: frag-native global->register, 2-deep set pipeline, counted VMCNT4.
// ---------------------------------------------------------------------------
#define MEMPIN asm volatile("" ::: "memory")
#define BAR __builtin_amdgcn_s_barrier()
#define VMCNT4 asm volatile("s_waitcnt vmcnt(4)" ::: "memory")
#define VMCNT0 asm volatile("s_waitcnt vmcnt(0)" ::: "memory")

__global__ __launch_bounds__(256, 2) void conv_mfma(
    const unsigned short* __restrict__ xp, const unsigned short* __restrict__ wtf,
    const float* __restrict__ wsc, const float* __restrict__ psp,
    const float* __restrict__ psn, float* __restrict__ out) {
  __shared__ char Astrip[65536];               // 4 rows x 64 px x 256B

  const int bid = blockIdx.x;
  const int wg = (bid & 7) * 98 + (bid >> 3);  // bijective XCD swizzle (784=8*98)
  const int b = wg / 49;
  const int t = wg - b * 49;
  const int r0 = (t << 6) / 56;                // top padded xp-row of strip

  const int tid = threadIdx.x;
  const int wv = tid >> 6;                     // N quarter 0..3
  const int l = tid & 63;

  // ---- A frag pixel bases (strip-relative, 64-px row stride)
  int pxb[4];
#pragma unroll
  for (int mi = 0; mi < 4; ++mi) {
    int m = (t << 6) + mi * 16 + (l & 15);
    int rv = m / 56, w = m - rv * 56;
    pxb[mi] = ((rv - r0) << 6) + w;
  }

  // ---- scalars preloaded
  float w0s = wsc[0], w1s = wsc[1], w2s = wsc[2], w3s = wsc[3];
  float p0 = psp[0], p1 = psp[1], p2 = psp[2], p3 = psp[3];
  float n0 = psn[0], n1 = psn[1], n2 = psn[2], n3 = psn[3];

  f32x4_t acc[4][4], oacc[4][4];
  const f32x4_t fz = {0.f, 0.f, 0.f, 0.f};
#pragma unroll
  for (int i = 0; i < 4; ++i)
#pragma unroll
    for (int j = 0; j < 4; ++j) { acc[i][j] = fz; oacc[i][j] = fz; }

  const char* xg = (const char*)xp;
  const char* wtb = (const char*)wtf + (wv << 12) + (l << 4);  // per-lane B base
  const unsigned a_gbbase = (unsigned)((b * 3364 + r0 * 58) * 256);

  // stage the 64KB strip for group gg (16 loads/thread)
#define STAGE_STRIP(gg)                                                        \
  {                                                                            \
    const char* s_ = xg + (unsigned)(gg)*13778944u + a_gbbase;                 \
    _Pragma("unroll")                                                          \
    for (int k_ = 0; k_ < 16; ++k_) {                                          \
      int idx_ = tid + (k_ << 8);                                              \
      int px_ = idx_ >> 4, sl_ = idx_ & 15;                                    \
      int sr_ = px_ >> 6, xc_ = px_ & 63;                                      \
      g2l16(s_ + (sr_ * 58 + xc_) * 256 +                                      \
                (((sl_ & 8) | ((sl_ & 7) ^ (xc_ & 7))) << 4),                  \
            Astrip + idx_ * 16);                                               \
    }                                                                          \
  }

#define LOADB(d0, d1, d2, d3, uu)                                              \
  {                                                                            \
    const char* p_ = wtb + (unsigned)(uu) * 16384u;                            \
    d0 = *(const bf16x8_t*)(p_);                                               \
    d1 = *(const bf16x8_t*)(p_ + 1024);                                        \
    d2 = *(const bf16x8_t*)(p_ + 2048);                                        \
    d3 = *(const bf16x8_t*)(p_ + 3072);                                        \
  }

  // A frag reads for k-half cc_ at tap offset tyo (8 ds_read_b128)
#define READA(cc_, tyo_)                                                       \
  {                                                                            \
    const int kj_ = ((cc_) << 2) + (l >> 4);                                   \
    _Pragma("unroll")                                                          \
    for (int mi = 0; mi < 4; ++mi) {                                           \
      int px_ = pxb[mi] + (tyo_);                                              \
      int base_ = (px_ << 8) + ((kj_ ^ (px_ & 7)) << 4);                       \
      ahi[mi] = *(const bf16x8_t*)(Astrip + base_);                            \
      alo[mi] = *(const bf16x8_t*)(Astrip + base_ + 128);                      \
    }                                                                          \
  }

  // two sweeps: 16 independent ahi-MFMAs, then 16 alo-MFMAs (chain gap 15)
#define MMA32(B0, B1, B2, B3)                                                  \
  __builtin_amdgcn_s_setprio(1);                                               \
  _Pragma("unroll")                                                            \
  for (int mi = 0; mi < 4; ++mi) {                                             \
    acc[mi][0] = __builtin_amdgcn_mfma_f32_16x16x32_bf16(ahi[mi], B0, acc[mi][0], 0, 0, 0); \
    acc[mi][1] = __builtin_amdgcn_mfma_f32_16x16x32_bf16(ahi[mi], B1, acc[mi][1], 0, 0, 0); \
    acc[mi][2] = __builtin_amdgcn_mfma_f32_16x16x32_bf16(ahi[mi], B2, acc[mi][2], 0, 0, 0); \
    acc[mi][3] = __builtin_amdgcn_mfma_f32_16x16x32_bf16(ahi[mi], B3, acc[mi][3], 0, 0, 0); \
  }                                                                            \
  _Pragma("unroll")                                                            \
  for (int mi = 0; mi < 4; ++mi) {                                             \
    acc[mi][0] = __builtin_amdgcn_mfma_f32_16x16x32_bf16(alo[mi], B0, acc[mi][0], 0, 0, 0); \
    acc[mi][1] = __builtin_amdgcn_mfma_f32_16x16x32_bf16(alo[mi], B1, acc[mi][1], 0, 0, 0); \
    acc[mi][2] = __builtin_amdgcn_mfma_f32_16x16x32_bf16(alo[mi], B2, acc[mi][2], 0, 0, 0); \
    acc[mi][3] = __builtin_amdgcn_mfma_f32_16x16x32_bf16(alo[mi], B3, acc[mi][3], 0, 0, 0); \
  }                                                                            \
  __builtin_amdgcn_s_setprio(0);

#define QUANTIZE(gg, ss)                                                       \
  {                                                                            \
    float sw = ((gg) & 2) ? (((gg) & 1) ? w3s : w2s) : (((gg) & 1) ? w1s : w0s); \
    float sp = ((gg) & 2) ? (((gg) & 1) ? p3 : p2) : (((gg) & 1) ? p1 : p0);   \
    float sn = ((gg) & 2) ? (((gg) & 1) ? n3 : n2) : (((gg) & 1) ? n1 : n0);   \
    float sq = (ss) ? sn : sp;                                                 \
    float rs = sw / sq;                                                        \
    float sm = (ss) ? -sq : sq;                                                \
    _Pragma("unroll")                                                          \
    for (int mi = 0; mi < 4; ++mi)                                             \
      _Pragma("unroll")                                                        \
      for (int ni = 0; ni < 4; ++ni)                                           \
        _Pragma("unroll")                                                      \
        for (int j = 0; j < 4; ++j) {                                          \
          float v = acc[mi][ni][j] * rs;                                       \
          v = fminf(fmaxf(v, -128.f), 127.f);                                  \
          oacc[mi][ni][j] += sm * rintf(v);                                    \
          acc[mi][ni][j] = 0.f;                                                \
        }                                                                      \
  }

  bf16x8_t ahi[4], alo[4];
  bf16x8_t bA0, bA1, bA2, bA3, bB0, bB1, bB2, bB3;

  // ---- prologue: strip(0) [16] then B(0), B(1) [8] in flight
  STAGE_STRIP(0);
  MEMPIN;
  LOADB(bA0, bA1, bA2, bA3, 0);
  LOADB(bB0, bB1, bB2, bB3, 1);

  int tap = 0, sgn = 0, g = 0;
  for (int v = 0; v < 72; ++v) {
    const int ty = tap / 3;
    const int tyo = (ty << 6) + (tap - ty * 3);

    // ---- even unit u=2v (cc=0), consumes set A
    VMCNT4;                       // strip (if pending) + B(2v) landed
    if (tap == 0) { BAR; }        // group entry: strip published by all waves
    MEMPIN;
    READA(0, tyo);
    MMA32(bA0, bA1, bA2, bA3);
    MEMPIN;
    if (v < 71) { LOADB(bA0, bA1, bA2, bA3, 2 * v + 2); }

    // ---- odd unit u=2v+1 (cc=1), consumes set B
    if (v == 71) { VMCNT0; } else { VMCNT4; }
    MEMPIN;
    READA(1, tyo);
    MMA32(bB0, bB1, bB2, bB3);

    if (tap == 8) {
      QUANTIZE(g, sgn);
      if (sgn == 1 && v < 71) {
        BAR;                      // all waves done reading strip(g)
        STAGE_STRIP(g + 1);       // republish before next B issue
      }
    }
    MEMPIN;
    if (v < 71) { LOADB(bB0, bB1, bB2, bB3, 2 * v + 3); }

    if (++tap == 9) { tap = 0; g += sgn; sgn ^= 1; }
  }

  // ---- store (64-px tiles are image-row-aligned: no masking needed)
#pragma unroll
  for (int ni = 0; ni < 4; ++ni) {
    int oc = (wv << 6) + ni * 16 + (l & 15);
    float* orow = out + ((size_t)(b * 256 + oc)) * 3136;
#pragma unroll
    for (int mi = 0; mi < 4; ++mi) {
      int m0 = (t << 6) + mi * 16 + ((l >> 4) << 2);
#pragma unroll
      for (int j = 0; j < 4; ++j) {
        orow[m0 + j] = oacc[mi][ni][j];
      }
    }
  }
#undef STAGE_STRIP
#undef LOADB
#undef READA
#undef MMA32
#undef QUANTIZE
}

// ---------------------------------------------------------------------------
// Fallback (ws too small): direct conv with inline weight quantization.
// ---------------------------------------------------------------------------
__global__ __launch_bounds__(256) void naive_conv(
    const float* __restrict__ x, const float* __restrict__ wgt,
    const float* __restrict__ wsc, const float* __restrict__ psp,
    const float* __restrict__ psn, float* __restrict__ out) {
  int idx = blockIdx.x * 256 + threadIdx.x;
  if (idx >= 12845056) return;
  int b = idx / 802816;
  int r = idx - b * 802816;
  int oc = r / 3136;
  int hw = r - oc * 3136;
  int h = hw / 56, w = hw - (hw / 56) * 56;
  float o = 0.f;
  for (int g = 0; g < 4; ++g) {
    float sw = wsc[g];
    float inv = 1.f / sw;
    float pp = 0.f, pn = 0.f;
    for (int tap = 0; tap < 9; ++tap) {
      int y = h + tap / 3 - 1, xx = w + tap % 3 - 1;
      if (y < 0 || y > 55 || xx < 0 || xx > 55) continue;
      const float* xr = x + (size_t)(b * 256 + g * 64) * 3136 + y * 56 + xx;
      const float* wrr = wgt + (size_t)oc * 2304 + (size_t)(g * 64) * 9 + tap;
      for (int c = 0; c < 64; ++c) {
        float xv = xr[(size_t)c * 3136];
        float rv = wrr[c * 9] * inv;
        pp += xv * rintf(fminf(fmaxf(rv, 0.f), 3.f));
        pn += xv * rintf(fminf(fmaxf(-rv, 0.f), 3.f));
      }
    }
    float sp = psp[g], sn = psn[g];
    o += rintf(fminf(fmaxf(pp * (sw / sp), -128.f), 127.f)) * sp;
    o -= rintf(fminf(fmaxf(pn * (sw / sn), -128.f), 127.f)) * sn;
  }
  out[idx] = o;
}

extern "C" void kernel_launch(void* const* d_in, const int* in_sizes, int n_in,
                              void* d_out, int out_size, void* d_ws, size_t ws_size,
                              hipStream_t stream) {
  const float* x = (const float*)d_in[0];
  const float* wgt = (const float*)d_in[1];
  const float* wsc = (const float*)d_in[2];
  const float* psp = (const float*)d_in[3];
  const float* psn = (const float*)d_in[4];
  float* out = (float*)d_out;

  if (ws_size >= (size_t)XP_BYTES + (size_t)WT_BYTES) {
    unsigned short* xpw = (unsigned short*)d_ws;
    unsigned short* wtw = (unsigned short*)((char*)d_ws + XP_BYTES);
    prep_x<<<3584, 256, 0, stream>>>(x, (__hip_bfloat16*)xpw);
    prep_w<<<576, 256, 0, stream>>>(wgt, wsc, wtw);
    conv_mfma<<<784, 256, 0, stream>>>(xpw, wtw, wsc, psp, psn, out);
  } else {
    naive_conv<<<(12845056 + 255) / 256, 256, 0, stream>>>(x, wgt, wsc, psp, psn, out);
  }
}